// Round 8
// baseline (316.042 us; speedup 1.0000x reference)
//
#include <hip/hip_runtime.h>

#define B_ 64
#define L_ 196
#define D_ 2048
#define I_ 512
#define M_ (B_*L_)   // 12544

typedef __attribute__((ext_vector_type(8))) short bf16x8;
typedef __attribute__((ext_vector_type(4))) float f32x4;
typedef unsigned short u16;

__device__ __forceinline__ u16 f2bf(float x){
  unsigned u = __float_as_uint(x);
  u += 0x7fffu + ((u >> 16) & 1u);
  return (u16)(u >> 16);
}

__device__ __forceinline__ void gld16(const void* g, void* l){
  __builtin_amdgcn_global_load_lds(
      (const __attribute__((address_space(1))) void*)g,
      (__attribute__((address_space(3))) void*)l, 16, 0, 0);
}

// gfx9 waitcnt imm: vmcnt[3:0]=bits3:0, expcnt=bits6:4, lgkmcnt=bits11:8, vmcnt[5:4]=bits15:14
template<int N> __device__ __forceinline__ void wait_vm(){
  __builtin_amdgcn_s_waitcnt((N&15) | ((N&48)<<10) | (7<<4) | (15<<8));
}
__device__ __forceinline__ void wait_lgkm0(){
  __builtin_amdgcn_s_waitcnt(15 | (48<<10) | (7<<4));   // vmcnt=63 (no wait), lgkmcnt=0
}
__device__ __forceinline__ void bar(){
  asm volatile("" ::: "memory");
  __builtin_amdgcn_s_barrier();
  asm volatile("" ::: "memory");
}

__device__ __forceinline__ unsigned cvtpk(float a, float b){
  unsigned r;
  asm("v_cvt_pk_bf16_f32 %0, %1, %2" : "=v"(r) : "v"(a), "v"(b));
  return r;
}

// Merged prep: transpose_cvt(W_f), transpose_cvt(W_a), hs — one launch (was 3).
// blocks [0,1024): W_f [2048,512] -> WfT; [1024,2048): W_a [512,2048] -> WaT;
// [2048,2560): hs[b][n] = b_h[n] + hidden[b]·W_h[:,n]  (k-split x4).
__launch_bounds__(256)
__global__ void prep_kernel(const float* __restrict__ Wf, u16* __restrict__ WfT,
                            const float* __restrict__ Wa, u16* __restrict__ WaT,
                            const float* __restrict__ hidden, const float* __restrict__ Wh,
                            const float* __restrict__ bh, float* __restrict__ hsbuf){
  __shared__ float tile[32][33];
  __shared__ float red[4][64];
  const int bid = blockIdx.x, tid = threadIdx.x;
  if (bid < 2048){
    const float* in; u16* out; int R, C, id;
    if (bid < 1024){ in = Wf; out = WfT; R = D_; C = I_; id = bid; }
    else           { in = Wa; out = WaT; R = I_; C = D_; id = bid - 1024; }
    const int nx = C/32;
    const int c0 = (id % nx)*32, r0 = (id / nx)*32;
    const int tx = tid & 31, ty = tid >> 5;           // (32,8) mapping, flat
    #pragma unroll
    for (int i=0;i<32;i+=8)
      tile[ty+i][tx] = in[(size_t)(r0+ty+i)*C + c0 + tx];
    __syncthreads();
    #pragma unroll
    for (int i=0;i<32;i+=8)
      out[(size_t)(c0+ty+i)*R + r0 + tx] = f2bf(tile[tx][ty+i]);
  } else {
    const int id = bid - 2048;                        // 0..511
    const int nl = tid & 63, kg = tid >> 6;
    const int n = (id & 7)*64 + nl, b = id >> 3;
    const float* hrow = hidden + b*I_;
    float a0=0.f, a1=0.f;
    #pragma unroll
    for (int k=kg*128; k<kg*128+128; k+=2){
      a0 = fmaf(hrow[k+0], Wh[(size_t)(k+0)*I_ + n], a0);
      a1 = fmaf(hrow[k+1], Wh[(size_t)(k+1)*I_ + n], a1);
    }
    red[kg][nl] = a0 + a1;
    __syncthreads();
    if (kg == 0)
      hsbuf[b*I_ + n] = bh[n] + (red[0][nl]+red[1][nl]) + (red[2][nl]+red[3][nl]);
  }
}

// GEMM1 (cvt fused): t = bf16(fv @ WfT^T + b_f + hs[batch])   [M,512]
// R8: same single-barrier reg-staged structure as R7 (measured: conflicts 0,
// FETCH 67 MB, 122->90 us) but 512-thread blocks: R7 was GRID-limited to 3.06
// blocks/CU = 12 waves/CU (Occ 23.6%).  8 waves/block x 3 blocks/CU (LDS 48 KB)
// = 24 waves/CU.  Per wave: 2x2 frags, 8 MFMA/iter, 4 A-loads + 1 B-load.
// BM=128, BN=64, BK=64, NIT=32, one barrier/iter.  XCD-chunked remap kept.
__launch_bounds__(512)
__global__ void gemm1_kernel(const float* __restrict__ A, const u16* __restrict__ Bt,
                             const float* __restrict__ bias, const float* __restrict__ hs,
                             u16* __restrict__ outb)
{
  constexpr int K = D_, BK = 64, NIT = K/BK;      // 32
  __shared__ __align__(16) u16 Als[2][128*64];    // 16 KB each (bf16)
  __shared__ __align__(16) u16 Bls[2][64*64];     // 8 KB each

  const int tid = threadIdx.x, lane = tid&63, wave = tid>>6;   // wave 0..7
  const int lid = blockIdx.y*8 + blockIdx.x;      // 0..783
  const int wid = (lid & 7)*98 + (lid >> 3);      // XCD-chunked, bijective
  const int m0 = (wid >> 3)*128, n0 = (wid & 7)*64;
  const int q = lane>>4, mr = lane&15;
  const int wm = (wave&3)*32, wn = (wave>>2)*32;  // 4x2 wave grid over 128x64

  // ---- staging geometry ----
  // A: per wave 16 rows x 64 k fp32 = 4 loads of f32x4; 16 lanes = one row (256B).
  const int a_r  = wave*16 + (lane>>4);           // +4 per issue u
  const int a_kc = lane&15;                       // 4-float chunk
  const float* Aw = A + (size_t)(m0 + a_r)*K + a_kc*4;
  // B: per wave 8 rows x 64 k bf16 = 1 load of bf16x8; 8 lanes = one row (128B).
  const int b_r  = wave*8 + (lane>>3);
  const int b_kc = lane&7;                        // 16B chunk
  const u16* Bw = Bt + (size_t)(n0 + b_r)*K + b_kc*8;

  // LDS write offsets (u16 units), XOR-swizzled by row&7 (R7-verified: 0 conflicts)
  int awo[4];
  #pragma unroll
  for (int u=0;u<4;++u){
    int r = a_r + u*4;
    awo[u] = r*64 + (((a_kc>>1) ^ (r&7))*8) + (a_kc&1)*4;
  }
  const int bwo = b_r*64 + ((b_kc ^ (b_r&7))*8);

  // frag read offsets; chunk = s*4+q, swizzled by row&7
  int aro[2][2], bro[2][2];
  #pragma unroll
  for (int s=0;s<2;++s){
    #pragma unroll
    for (int i2=0;i2<2;++i2){
      int r = wm + i2*16 + mr;
      aro[s][i2] = r*64 + (((s*4+q) ^ (r&7))*8);
    }
    #pragma unroll
    for (int j=0;j<2;++j){
      int r = wn + j*16 + mr;
      bro[s][j] = r*64 + (((s*4+q) ^ (r&7))*8);
    }
  }

  f32x4 rA[4]; bf16x8 rB;
  f32x4 acc[2][2];
  #pragma unroll
  for (int i=0;i<2;++i)
    #pragma unroll
    for (int j=0;j<2;++j) acc[i][j] = (f32x4){0.f,0.f,0.f,0.f};

#define G1_LOAD(k0) { \
  _Pragma("unroll") \
  for (int u=0;u<4;++u) rA[u] = *(const f32x4*)(Aw + (size_t)(u*4)*K + (k0)); \
  rB = *(const bf16x8*)(Bw + (k0)); }

#define G1_CVTWR(bi) { \
  u16* Ab_ = Als[bi]; u16* Bb_ = Bls[bi]; \
  _Pragma("unroll") \
  for (int u=0;u<4;++u){ \
    unsigned lo = cvtpk(rA[u][0], rA[u][1]); \
    unsigned hi = cvtpk(rA[u][2], rA[u][3]); \
    *(uint2*)(Ab_ + awo[u]) = make_uint2(lo, hi); \
  } \
  *(bf16x8*)(Bb_ + bwo) = rB; }

  // prologue: tile0 -> regs -> LDS buf0; tile1 -> regs
  G1_LOAD(0)
  G1_CVTWR(0)
  G1_LOAD(BK)
  wait_lgkm0(); bar();

  for (int t=0; t<NIT; ++t){
    if (t+1 < NIT) G1_CVTWR((t+1)&1)      // consumes rA/rB (auto vmcnt wait)
    if (t+2 < NIT) G1_LOAD((t+2)*BK)      // refill regs for tile t+2
    const u16* Ab = Als[t&1];
    const u16* Bb = Bls[t&1];
    #pragma unroll
    for (int s=0;s<2;++s){
      bf16x8 af[2], bg[2];
      #pragma unroll
      for (int i2=0;i2<2;++i2) af[i2] = *(const bf16x8*)(Ab + aro[s][i2]);
      #pragma unroll
      for (int j=0;j<2;++j)    bg[j]  = *(const bf16x8*)(Bb + bro[s][j]);
      #pragma unroll
      for (int i2=0;i2<2;++i2)
        #pragma unroll
        for (int j=0;j<2;++j)
          acc[i2][j] = __builtin_amdgcn_mfma_f32_16x16x32_bf16(af[i2], bg[j], acc[i2][j], 0,0,0);
    }
    wait_lgkm0();      // all LDS ops drained before raw barrier
    bar();
  }

  #pragma unroll
  for (int i2=0;i2<2;++i2){
    #pragma unroll
    for (int j=0;j<2;++j){
      int gcol = n0 + wn + j*16 + mr;
      float bcol = bias[gcol];
      #pragma unroll
      for (int r=0;r<4;++r){
        int grow = m0 + wm + i2*16 + q*4 + r;
        int batch = grow / L_;
        outb[(size_t)grow*I_ + gcol] = f2bf(acc[i2][j][r] + bcol + hs[batch*I_ + gcol]);
      }
    }
  }
#undef G1_LOAD
#undef G1_CVTWR
}

// Fused GEMM2 + softmax + z.  BN=64: block = (batch b, 64 e-cols), each wave owns 16 cols.
// Round-0 best-measured version (unchanged).
__launch_bounds__(256)
__global__ void gemm2_fused_kernel(const u16* __restrict__ T, const u16* __restrict__ Wa,
                                   const float* __restrict__ b_a, const float* __restrict__ fv,
                                   float* __restrict__ out)
{
  constexpr int K = I_, BK = 32, NIT = K/BK;     // 16
  __shared__ __align__(16) u16 Als[2][256*32];   // 16 KB each (rows 196..255 staged, masked)
  __shared__ __align__(16) u16 Bls[2][64*32];    // 4 KB each

  const int tid = threadIdx.x, lane = tid&63, wave = tid>>6;
  const int b = blockIdx.y, n0 = blockIdx.x*64;
  const int q = lane>>4, mr = lane&15;
  const int l16 = lane>>2, kc4 = (lane&3)^(l16&3);

  // A: 16 issues of 16 rows x 32 k; wave takes 4
  const u16* Ag[4]; int Alo[4];
  #pragma unroll
  for (int u=0;u<4;++u){
    int j = wave*4+u;
    int grow = b*L_ + j*16 + l16; if (grow > M_-1) grow = M_-1;   // clamp (masked later)
    Ag[u] = T + (size_t)grow*K + kc4*8; Alo[u] = j*512;
  }
  // B: 4 issues; wave takes 1
  const u16* Bg = Wa + (size_t)(n0 + wave*16 + l16)*K + kc4*8;
  const int  Blo = wave*512;

  const int abase = mr*32 + ((q ^ (mr&3))*8);    // + i*512 per frag
  const int col  = n0 + wave*16 + mr;            // this lane's e-column
  const int boff = (wave*16+mr)*32 + ((q ^ (mr&3))*8);

  f32x4 acc[13];
  #pragma unroll
  for (int i=0;i<13;i++) acc[i] = (f32x4){0,0,0,0};

  // preload tiles 0,1 (10 outstanding per wave)
  #pragma unroll
  for (int u=0;u<4;++u) gld16(Ag[u],    &Als[0][Alo[u]]);
  gld16(Bg,    &Bls[0][Blo]);
  #pragma unroll
  for (int u=0;u<4;++u) gld16(Ag[u]+BK, &Als[1][Alo[u]]);
  gld16(Bg+BK, &Bls[1][Blo]);

  for (int it=0; it<NIT; ++it){
    if (it+1<NIT) wait_vm<5>(); else wait_vm<0>();
    bar();
    const u16* Ab = Als[it&1];
    const u16* Bb = Bls[it&1];
    bf16x8 bg0 = *(const bf16x8*)(Bb + boff);
    bf16x8 af[13];
    #pragma unroll
    for (int i=0;i<13;++i) af[i] = *(const bf16x8*)(Ab + abase + i*512);
    wait_lgkm0();
    bar();
    if (it+2<NIT){
      int k0 = (it+2)*BK;
      #pragma unroll
      for (int u=0;u<4;++u) gld16(Ag[u]+k0, &Als[it&1][Alo[u]]);
      gld16(Bg+k0, &Bls[it&1][Blo]);
    }
    #pragma unroll
    for (int i=0;i<13;++i)
      acc[i] = __builtin_amdgcn_mfma_f32_16x16x32_bf16(af[i], bg0, acc[i], 0,0,0);
  }

  // ---- fused epilogue: e = acc + b_a; softmax over 196 rows; alpha + z ----
  const bool v12 = (q == 0);                     // frag 12: rows 192..195 valid only for q==0
  float bc = b_a[col];
  #pragma unroll
  for (int i=0;i<13;++i)
    #pragma unroll
    for (int r=0;r<4;++r) acc[i][r] += bc;

  float m = -3.4e38f;
  #pragma unroll
  for (int i=0;i<12;++i)
    #pragma unroll
    for (int r=0;r<4;++r) m = fmaxf(m, acc[i][r]);
  if (v12)
    #pragma unroll
    for (int r=0;r<4;++r) m = fmaxf(m, acc[12][r]);
  m = fmaxf(m, __shfl_xor(m, 16));
  m = fmaxf(m, __shfl_xor(m, 32));

  float s = 0.f;
  #pragma unroll
  for (int i=0;i<12;++i)
    #pragma unroll
    for (int r=0;r<4;++r){ float e = __expf(acc[i][r]-m); acc[i][r] = e; s += e; }
  if (v12)
    #pragma unroll
    for (int r=0;r<4;++r){ float e = __expf(acc[12][r]-m); acc[12][r] = e; s += e; }
  s += __shfl_xor(s, 16);
  s += __shfl_xor(s, 32);
  float inv = 1.f/s;

  float* alpha = out + (size_t)B_*D_ + (size_t)b*L_*D_;
  const float* fvb = fv + (size_t)b*L_*D_;
  float z = 0.f;
  #pragma unroll
  for (int i=0;i<13;++i){
    if (i < 12 || v12){
      #pragma unroll
      for (int r=0;r<4;++r){
        int row = i*16 + q*4 + r;               // < 196 when valid
        float a = acc[i][r] * inv;
        alpha[(size_t)row*D_ + col] = a;
        z = fmaf(a, fvb[(size_t)row*D_ + col], z);
      }
    }
  }
  z += __shfl_xor(z, 16);
  z += __shfl_xor(z, 32);
  if (q == 0) out[(size_t)b*D_ + col] = z;
}

extern "C" void kernel_launch(void* const* d_in, const int* in_sizes, int n_in,
                              void* d_out, int out_size, void* d_ws, size_t ws_size,
                              hipStream_t stream){
  (void)in_sizes; (void)n_in; (void)out_size; (void)ws_size;
  const float* fv     = (const float*)d_in[0];
  const float* hidden = (const float*)d_in[1];
  const float* W_f    = (const float*)d_in[2];
  const float* b_f    = (const float*)d_in[3];
  const float* W_h    = (const float*)d_in[4];
  const float* b_h    = (const float*)d_in[5];
  const float* W_a    = (const float*)d_in[6];
  const float* b_a    = (const float*)d_in[7];
  float* out = (float*)d_out;

  char* ws = (char*)d_ws;
  u16*   t_bf  = (u16*)ws;                     // 12,845,056 B
  u16*   WfT   = (u16*)(ws + 12845056);        //  2,097,152 B
  u16*   WaT   = (u16*)(ws + 14942208);        //  2,097,152 B
  float* hsbuf = (float*)(ws + 17039360);      //    131,072 B

  prep_kernel<<<2560, 256, 0, stream>>>(W_f, WfT, W_a, WaT, hidden, W_h, b_h, hsbuf);
  gemm1_kernel<<<dim3(8, M_/128), 512, 0, stream>>>(fv, WfT, b_f, hsbuf, t_bf);
  gemm2_fused_kernel<<<dim3(D_/64, B_), 256, 0, stream>>>(t_bf, WaT, b_a, fv, out);
}